// Round 5
// baseline (1327.204 us; speedup 1.0000x reference)
//
#include <hip/hip_runtime.h>
#include <hip/hip_bf16.h>
#include <stdint.h>

#define B_TOTAL 262144
#define TB 64
#define RECORD 2560         // 10 stream-slots * 256B per row
#define LDS_BYTES 163840    // 64 rows * 2560 = 160 KiB exactly
#define HEAD_W 204800       // bf16 weight elements per head in d_ws

typedef short v8s __attribute__((ext_vector_type(8)));
typedef float v4f __attribute__((ext_vector_type(4)));

union Frag { uint4 q; uint32_t d[4]; v8s v; };

__device__ __forceinline__ uint32_t pack2(float a, float b) {
    union { __hip_bfloat162 h; uint32_t u; } p;
    p.h = __float22bfloat162_rn(make_float2(a, b));
    return p.u;
}

// LDS layout: addr(row, slot, gg) = row*2560 + slot*256 + ((gg ^ (row&15))<<4)
// Row stride 2560 and slot stride 256 are both ==0 mod 256; swizzle lives in
// bits 4..7 -> XOR with compile-time (gg<<4) folds into per-lane base regs;
// slot / row-tile offsets are DS 16-bit immediates. Zero per-access VALU.

struct KParams {
    const float* x; const float* u; const float* mix; const float* P;
    const float* mb[6];
    const float* tb[6];
    const float* Wout[2];
    const float* bout[2];
    const unsigned short* wbf;
    float* out;
};

struct PrepParams { const float* src[12]; unsigned short* dst; };

__global__ __launch_bounds__(256) void prep_kernel(PrepParams pp) {
    const int ends[12] = {16384,81920,98304,163840,172032,204800,
                          221184,286720,303104,368640,376832,409600};
    int gi = (blockIdx.x * 256 + threadIdx.x) * 4;
    if (gi >= 409600) return;
    int s = 0;
    #pragma unroll
    for (int i = 0; i < 12; ++i) { if (gi >= ends[i]) s = i + 1; }
    int base = (s == 0) ? 0 : ends[s - 1];
    const float4 f = *(const float4*)(pp.src[s] + (gi - base));
    *(uint2*)(pp.dst + gi) = make_uint2(pack2(f.x, f.y), pack2(f.z, f.w));
}

__device__ __forceinline__ void stage_xu(char* lds, const float* x, const float* u,
                                         int rowBase, int tid)
{
    // 64 rows * 16 granules = 1024 granule-writes, one per thread
    const int row = tid >> 4;
    const int gg  = tid & 15;
    const int grow = rowBase + row;
    float4 fa, fb;
    if (gg < 12) {
        const float* s2 = x + grow * 96 + gg * 8;
        fa = *(const float4*)s2; fb = *(const float4*)(s2 + 4);
    } else {
        const float* s2 = u + grow * 32 + (gg - 12) * 8;
        fa = *(const float4*)s2; fb = *(const float4*)(s2 + 4);
    }
    *(uint4*)(lds + row * RECORD + ((gg ^ (row & 15)) << 4)) =
        make_uint4(pack2(fa.x, fa.y), pack2(fa.z, fa.w),
                   pack2(fb.x, fb.y), pack2(fb.z, fb.w));
}

// Pre-loaded per-phase state: all 20 weight fragments + biases, in registers.
// Issued BEFORE the phase barrier; with waves_per_eu(4,4) the compiler gets a
// firm 128-reg budget and staggers the loads without spilling (round-0-verified
// at even higher nominal pressure). Biases fold into the MFMA C-init.
struct WPre { Frag w[20]; float4 mB; float4 tB[4]; };

template<int N>
__device__ __forceinline__ WPre preload(const unsigned short* W, int colBase,
        const float* mbias, const float* tbias, int lane)
{
    WPre r;
    const int l15  = lane & 15;
    const int quad = lane >> 4;
    const unsigned short* wRow = W + (colBase + l15) * 128 + quad * 8;
    #pragma unroll
    for (int s = 0; s < 5; ++s)
        #pragma unroll
        for (int ks = 0; ks < 4; ++ks)
            r.w[s * 4 + ks].q = *(const uint4*)(wRow + s * (N * 128) + ks * 32);
    const int obase = colBase + quad * 4;
    r.mB = *(const float4*)(mbias + obase);
    #pragma unroll
    for (int s = 0; s < 4; ++s)
        r.tB[s] = *(const float4*)(tbias + s * N + obase);
    return r;
}

// 16 waves, TB=64. N=128 phases: wave = (colGroup 0..7, rowHalf 0..1),
// NBT=2 row-tiles. Final N=64: wave = (colGroup 0..3, rowTile 0..3), NBT=1,
// fused combine + Wout dot -> pgrid. MFMA: A = weight frag (m = out col),
// B = activation frag (n = batch row). Acc per lane: row bt*16+(lane&15),
// col obase+(lane>>4)*4+r. ldsR = lds pre-offset by the wave's row-tile base.
template<bool SHARED_IN, int N, int INS, int OUTS, int NBT>
__device__ __forceinline__ void compute(char* ldsR,
        const WPre& wp, float c0, const float* cP, int lane, int colBase,
        const float* Wout, float* pgrid, int prow)
{
    constexpr bool FINAL = (N == 64);
    const int l15  = lane & 15;
    const int quad = lane >> 4;

    // rb: bits 0..3 = 0, bits 4..7 = l15 (swizzle field), high bits = row*2560
    const uint32_t rb = (uint32_t)l15 * RECORD + ((uint32_t)l15 << 4);
    uint32_t rA[4];
    #pragma unroll
    for (int ks = 0; ks < 4; ++ks)
        rA[ks] = rb ^ (uint32_t)(((ks << 2) | quad) << 4);

    // Bias-initialized accumulators (MFMA C-in)
    v4f acc[5][NBT];
    #pragma unroll
    for (int bt = 0; bt < NBT; ++bt) {
        acc[0][bt] = (v4f){wp.mB.x, wp.mB.y, wp.mB.z, wp.mB.w};
        #pragma unroll
        for (int s = 0; s < 4; ++s)
            acc[s + 1][bt] = (v4f){wp.tB[s].x, wp.tB[s].y, wp.tB[s].z, wp.tB[s].w};
    }

    #pragma unroll
    for (int ks = 0; ks < 4; ++ks) {
        Frag xS[NBT];
        if constexpr (SHARED_IN) {
            #pragma unroll
            for (int bt = 0; bt < NBT; ++bt)
                xS[bt].q = *(const uint4*)(ldsR + rA[ks]
                            + (uint32_t)(bt * 40960 + INS * 256));
        }
        #pragma unroll
        for (int s = 0; s < 5; ++s) {
            Frag xF[NBT];
            if constexpr (!SHARED_IN) {
                #pragma unroll
                for (int bt = 0; bt < NBT; ++bt)
                    xF[bt].q = *(const uint4*)(ldsR + rA[ks]
                                + (uint32_t)(bt * 40960 + (INS + s) * 256));
            }
            #pragma unroll
            for (int bt = 0; bt < NBT; ++bt)
                acc[s][bt] = __builtin_amdgcn_mfma_f32_16x16x32_bf16(
                    wp.w[s * 4 + ks].v, (SHARED_IN ? xS[bt].v : xF[bt].v),
                    acc[s][bt], 0, 0, 0);
        }
    }

    const int obase = colBase + (quad << 2);

    if constexpr (!FINAL) {
        // write base: granule slot = (obase>>3) ^ (row&15); sub-offset (obase&7)*2
        const int ocg = (colBase >> 3) + (quad >> 1);
        const uint32_t w0 = (rb ^ ((uint32_t)ocg << 4)) + (uint32_t)((quad & 1) << 3);
        #pragma unroll
        for (int bt = 0; bt < NBT; ++bt) {
            char* ab = ldsR + (w0 + (uint32_t)(bt * 40960));
            float vr[4];
            vr[0] = c0 * acc[0][bt][0];
            vr[1] = c0 * acc[0][bt][1];
            vr[2] = c0 * acc[0][bt][2];
            vr[3] = c0 * acc[0][bt][3];
            uint2 tw[4];
            #pragma unroll
            for (int s = 0; s < 4; ++s) {
                const float t0 = acc[s + 1][bt][0];
                const float t1 = acc[s + 1][bt][1];
                const float t2 = acc[s + 1][bt][2];
                const float t3 = acc[s + 1][bt][3];
                vr[0] = fmaf(cP[s], t0, vr[0]);
                vr[1] = fmaf(cP[s], t1, vr[1]);
                vr[2] = fmaf(cP[s], t2, vr[2]);
                vr[3] = fmaf(cP[s], t3, vr[3]);
                tw[s] = make_uint2(pack2(fmaxf(t0, 0.f), fmaxf(t1, 0.f)),
                                   pack2(fmaxf(t2, 0.f), fmaxf(t3, 0.f)));
            }
            *(uint2*)(ab + OUTS * 256) =
                make_uint2(pack2(fmaxf(vr[0], 0.f), fmaxf(vr[1], 0.f)),
                           pack2(fmaxf(vr[2], 0.f), fmaxf(vr[3], 0.f)));
            #pragma unroll
            for (int s = 0; s < 4; ++s)
                *(uint2*)(ab + (OUTS + 1 + s) * 256) = tw[s];
        }
    } else {
        const float4 wo = *(const float4*)(Wout + obase);
        float vr[4];
        vr[0] = c0 * acc[0][0][0];
        vr[1] = c0 * acc[0][0][1];
        vr[2] = c0 * acc[0][0][2];
        vr[3] = c0 * acc[0][0][3];
        #pragma unroll
        for (int s = 0; s < 4; ++s) {
            vr[0] = fmaf(cP[s], acc[s + 1][0][0], vr[0]);
            vr[1] = fmaf(cP[s], acc[s + 1][0][1], vr[1]);
            vr[2] = fmaf(cP[s], acc[s + 1][0][2], vr[2]);
            vr[3] = fmaf(cP[s], acc[s + 1][0][3], vr[3]);
        }
        float pp = fmaxf(vr[0], 0.f) * wo.x + fmaxf(vr[1], 0.f) * wo.y
                 + fmaxf(vr[2], 0.f) * wo.z + fmaxf(vr[3], 0.f) * wo.w;
        pp += __shfl_xor(pp, 16);
        pp += __shfl_xor(pp, 32);
        if (lane < 16)
            pgrid[(colBase >> 4) * 64 + prow + lane] = pp;
    }
}

// waves_per_eu(4,4): pin BOTH min and max -> firm 128-VGPR budget.
// (__launch_bounds__' 2nd arg sets only the MIN; rounds 1/3/4 showed the
// compiler then targets 8 waves/EU -> 64-84 regs -> serialization or spill.)
extern "C" __global__ __launch_bounds__(1024)
__attribute__((amdgpu_waves_per_eu(4, 4)))
void critic_kernel(KParams p)
{
    extern __shared__ char lds[];
    const int tid  = threadIdx.x;
    const int lane = tid & 63;
    const int wave = tid >> 6;            // 0..15
    const int rowBase = blockIdx.x * TB;

    // N=128 phases: colGroup = wave&7, rowHalf = wave>>3 (2 row-tiles each)
    const int cb128 = (wave & 7) << 4;
    char* ldsH = lds + ((wave >> 3) * 81920);
    // Final N=64 phase: colGroup = wave&3, rowTile = wave>>2 (1 row-tile)
    const int cb64 = (wave & 3) << 4;
    const int rt64 = wave >> 2;
    char* ldsF = lds + rt64 * 40960;

    const float m  = p.mix[0];
    const float c0 = 1.f - m;
    float cP[4];
    #pragma unroll
    for (int k = 0; k < 4; ++k) cP[k] = m * p.P[k];

    stage_xu(lds, p.x, p.u, rowBase, tid);

    #pragma unroll 1
    for (int head = 0; head < 2; ++head) {
        const unsigned short* wb = p.wbf + head * HEAD_W;
        const int hb = head * 3;

        // Preload phase weights BEFORE each barrier: L2 latency overlaps
        // the barrier wait + previous phase's epilogue.
        WPre w1 = preload<128>(wb, cb128, p.mb[hb + 0], p.tb[hb + 0], lane);
        __syncthreads();
        // L1: xu (slot 0, shared) -> slots 5..9 (5 relu'd streams)
        compute<true, 128, 0, 5, 2>(ldsH, w1, c0, cP, lane, cb128,
                                    nullptr, nullptr, 0);

        WPre w2 = preload<128>(wb + 81920, cb128, p.mb[hb + 1], p.tb[hb + 1], lane);
        __syncthreads();
        // L2: slots 5..9 -> slots 0..4 (overwrites xu slot)
        compute<false, 128, 5, 0, 2>(ldsH, w2, c0, cP, lane, cb128,
                                     nullptr, nullptr, 0);

        WPre w3 = preload<64>(wb + 163840, cb64, p.mb[hb + 2], p.tb[hb + 2], lane);
        __syncthreads();
        // L3 + L4: slots 0..4 -> register combine -> dot(Wout) -> pgrid
        // pgrid lives at bytes [1280,2304) = row0's slots 5..9 (free during L3)
        compute<false, 64, 0, 0, 1>(ldsF, w3, c0, cP, lane, cb64,
                                    p.Wout[head], (float*)(lds + 1280), rt64 * 16);
        __syncthreads();

        if (tid < 64) {
            const float* pg = (const float*)(lds + 1280);
            p.out[head * B_TOTAL + rowBase + tid] =
                p.bout[head][0] + pg[tid] + pg[64 + tid] + pg[128 + tid] + pg[192 + tid];
        }
        if (head == 0) {
            stage_xu(lds, p.x, p.u, rowBase, tid);   // L2 overwrote xu; restage
        }
    }
}

extern "C" void kernel_launch(void* const* d_in, const int* in_sizes, int n_in,
                              void* d_out, int out_size, void* d_ws, size_t ws_size,
                              hipStream_t stream)
{
    (void)in_sizes; (void)n_in; (void)out_size; (void)ws_size;

    PrepParams pp;
    const int sidx[12] = {4, 20, 6, 22, 8, 24, 12, 26, 14, 28, 16, 30};
    for (int i = 0; i < 12; ++i) pp.src[i] = (const float*)d_in[sidx[i]];
    pp.dst = (unsigned short*)d_ws;

    KParams kp;
    kp.x = (const float*)d_in[0];  kp.u = (const float*)d_in[1];
    kp.mix = (const float*)d_in[2]; kp.P = (const float*)d_in[3];
    const int mbi[6] = {5, 7, 9, 13, 15, 17};
    const int tbi[6] = {21, 23, 25, 27, 29, 31};
    for (int i = 0; i < 6; ++i) {
        kp.mb[i] = (const float*)d_in[mbi[i]];
        kp.tb[i] = (const float*)d_in[tbi[i]];
    }
    kp.Wout[0] = (const float*)d_in[10]; kp.Wout[1] = (const float*)d_in[18];
    kp.bout[0] = (const float*)d_in[11]; kp.bout[1] = (const float*)d_in[19];
    kp.wbf = (const unsigned short*)d_ws;
    kp.out = (float*)d_out;

    (void)hipFuncSetAttribute((const void*)critic_kernel,
                              hipFuncAttributeMaxDynamicSharedMemorySize, LDS_BYTES);

    hipLaunchKernelGGL(prep_kernel, dim3(400), dim3(256), 0, stream, pp);
    hipLaunchKernelGGL(critic_kernel, dim3(B_TOTAL / TB), dim3(1024), LDS_BYTES, stream, kp);
}

// Round 6
// 873.763 us; speedup vs baseline: 1.5190x; 1.5190x over previous
//
#include <hip/hip_runtime.h>
#include <hip/hip_bf16.h>
#include <stdint.h>

#define B_TOTAL 262144
#define TB 64
#define RECORD 1280         // 5 stream-slots * 256B per row (in-place phase reuse)
#define LDS_BYTES 81920     // 64 rows * 1280 = 80 KiB -> 2 blocks/CU
#define HEAD_W 204800       // bf16 weight elements per head in d_ws

typedef short v8s __attribute__((ext_vector_type(8)));
typedef float v4f __attribute__((ext_vector_type(4)));

union Frag { uint4 q; uint32_t d[4]; v8s v; };

__device__ __forceinline__ uint32_t pack2(float a, float b) {
    union { __hip_bfloat162 h; uint32_t u; } p;
    p.h = __float22bfloat162_rn(make_float2(a, b));
    return p.u;
}

// LDS layout: addr(row, slot, gg) = row*1280 + slot*256 + ((gg ^ (row&15))<<4)
// Row stride 1280 and slot stride 256 are ==0 mod 256; swizzle bits 4..7 fold
// into per-lane base regs; slot / row-tile offsets are DS 16-bit immediates
// (max 3*20480+4*256 = 62464 < 64K). Zero per-access VALU.
//
// IN-PLACE slot discipline (the 80 KiB trick): each phase reads EVERY byte of
// its input slots into registers, then after a barrier the epilogue rewrites
// the SAME slots. One extra barrier per phase buys 2 blocks/CU (16 waves/CU).

struct KParams {
    const float* x; const float* u; const float* mix; const float* P;
    const float* mb[6];
    const float* tb[6];
    const float* Wout[2];
    const float* bout[2];
    const unsigned short* wbf;
    float* out;
};

struct PrepParams { const float* src[12]; unsigned short* dst; };

__global__ __launch_bounds__(256) void prep_kernel(PrepParams pp) {
    const int ends[12] = {16384,81920,98304,163840,172032,204800,
                          221184,286720,303104,368640,376832,409600};
    int gi = (blockIdx.x * 256 + threadIdx.x) * 4;
    if (gi >= 409600) return;
    int s = 0;
    #pragma unroll
    for (int i = 0; i < 12; ++i) { if (gi >= ends[i]) s = i + 1; }
    int base = (s == 0) ? 0 : ends[s - 1];
    const float4 f = *(const float4*)(pp.src[s] + (gi - base));
    *(uint2*)(pp.dst + gi) = make_uint2(pack2(f.x, f.y), pack2(f.z, f.w));
}

__device__ __forceinline__ void stage_xu(char* lds, const float* x, const float* u,
                                         int rowBase, int tid)
{
    // 64 rows * 16 granules = 1024 granule-writes into slot 0
    for (int G = tid; G < 1024; G += 512) {
        const int row = G >> 4;
        const int gg  = G & 15;
        const int grow = rowBase + row;
        float4 fa, fb;
        if (gg < 12) {
            const float* s2 = x + grow * 96 + gg * 8;
            fa = *(const float4*)s2; fb = *(const float4*)(s2 + 4);
        } else {
            const float* s2 = u + grow * 32 + (gg - 12) * 8;
            fa = *(const float4*)s2; fb = *(const float4*)(s2 + 4);
        }
        *(uint4*)(lds + row * RECORD + ((gg ^ (row & 15)) << 4)) =
            make_uint4(pack2(fa.x, fa.y), pack2(fa.z, fa.w),
                       pack2(fb.x, fb.y), pack2(fb.z, fb.w));
    }
}

// Pre-loaded per-phase state: all 20 weight fragments + biases, in registers.
// R0/R2-verified: with __launch_bounds__(512,2) this compiles to 128 VGPR with
// staggered (non-serialized) loads and no scratch. DO NOT change the bounds or
// the WPre-before-barrier shape — every other config collapsed (R1/R3/R4/R5).
struct WPre { Frag w[20]; float4 mB; float4 tB[4]; };

template<int N>
__device__ __forceinline__ WPre preload(const unsigned short* W, int colBase,
        const float* mbias, const float* tbias, int lane)
{
    WPre r;
    const int l15  = lane & 15;
    const int quad = lane >> 4;
    const unsigned short* wRow = W + (colBase + l15) * 128 + quad * 8;
    #pragma unroll
    for (int s = 0; s < 5; ++s)
        #pragma unroll
        for (int ks = 0; ks < 4; ++ks)
            r.w[s * 4 + ks].q = *(const uint4*)(wRow + s * (N * 128) + ks * 32);
    const int obase = colBase + quad * 4;
    r.mB = *(const float4*)(mbias + obase);
    #pragma unroll
    for (int s = 0; s < 4; ++s)
        r.tB[s] = *(const float4*)(tbias + s * N + obase);
    return r;
}

// MFMA phase: reads input slots -> bias-initialized acc. No LDS writes here.
// SHARED_IN: all 5 streams read the shared xu (slot 0). Else stream s reads
// slot s. btOff: runtime row-tile byte base (final phase row-half).
// MFMA: A = weight frag (m = out col), B = activation frag (n = batch row).
// Acc per lane: batch row bt*16+(lane&15), out cols obase+(lane>>4)*4+r.
template<bool SHARED_IN, int NBT>
__device__ __forceinline__ void mfma_phase(const char* lds, uint32_t btOff,
        const WPre& wp, v4f (&acc)[5][NBT], int lane)
{
    const int l15  = lane & 15;
    const int quad = lane >> 4;

    // rb bits 4..7 = l15 (swizzle field); l15*1280 and btOff are mod-256 clean.
    const uint32_t rb = (uint32_t)l15 * RECORD + ((uint32_t)l15 << 4) + btOff;
    uint32_t rA[4];
    #pragma unroll
    for (int ks = 0; ks < 4; ++ks)
        rA[ks] = rb ^ (uint32_t)(((ks << 2) | quad) << 4);

    #pragma unroll
    for (int bt = 0; bt < NBT; ++bt) {
        acc[0][bt] = (v4f){wp.mB.x, wp.mB.y, wp.mB.z, wp.mB.w};
        #pragma unroll
        for (int s = 0; s < 4; ++s)
            acc[s + 1][bt] = (v4f){wp.tB[s].x, wp.tB[s].y, wp.tB[s].z, wp.tB[s].w};
    }

    #pragma unroll
    for (int ks = 0; ks < 4; ++ks) {
        Frag xS[NBT];
        if constexpr (SHARED_IN) {
            #pragma unroll
            for (int bt = 0; bt < NBT; ++bt)
                xS[bt].q = *(const uint4*)(lds + rA[ks] + (uint32_t)(bt * 20480));
        }
        #pragma unroll
        for (int s = 0; s < 5; ++s) {
            Frag xF[NBT];
            if constexpr (!SHARED_IN) {
                #pragma unroll
                for (int bt = 0; bt < NBT; ++bt)
                    xF[bt].q = *(const uint4*)(lds + rA[ks]
                                + (uint32_t)(bt * 20480 + s * 256));
            }
            #pragma unroll
            for (int bt = 0; bt < NBT; ++bt)
                acc[s][bt] = __builtin_amdgcn_mfma_f32_16x16x32_bf16(
                    wp.w[s * 4 + ks].v, (SHARED_IN ? xS[bt].v : xF[bt].v),
                    acc[s][bt], 0, 0, 0);
        }
    }
}

// Epilogue (after the reads-done barrier): mix + relu, write the 5 streams
// back IN-PLACE into slots 0..4 (main -> slot 0, teacher s -> slot 1+s).
__device__ __forceinline__ void write_streams(char* lds, v4f (&acc)[5][4],
        float c0, const float* cP, int lane, int colBase)
{
    const int l15  = lane & 15;
    const int quad = lane >> 4;
    const uint32_t rb = (uint32_t)l15 * RECORD + ((uint32_t)l15 << 4);
    const int obase = colBase + (quad << 2);
    const int ocg = (colBase >> 3) + (quad >> 1);
    const uint32_t w0 = (rb ^ ((uint32_t)ocg << 4)) + (uint32_t)((quad & 1) << 3);
    #pragma unroll
    for (int bt = 0; bt < 4; ++bt) {
        char* ab = lds + (w0 + (uint32_t)(bt * 20480));
        float vr[4];
        vr[0] = c0 * acc[0][bt][0];
        vr[1] = c0 * acc[0][bt][1];
        vr[2] = c0 * acc[0][bt][2];
        vr[3] = c0 * acc[0][bt][3];
        uint2 tw[4];
        #pragma unroll
        for (int s = 0; s < 4; ++s) {
            const float t0 = acc[s + 1][bt][0];
            const float t1 = acc[s + 1][bt][1];
            const float t2 = acc[s + 1][bt][2];
            const float t3 = acc[s + 1][bt][3];
            vr[0] = fmaf(cP[s], t0, vr[0]);
            vr[1] = fmaf(cP[s], t1, vr[1]);
            vr[2] = fmaf(cP[s], t2, vr[2]);
            vr[3] = fmaf(cP[s], t3, vr[3]);
            tw[s] = make_uint2(pack2(fmaxf(t0, 0.f), fmaxf(t1, 0.f)),
                               pack2(fmaxf(t2, 0.f), fmaxf(t3, 0.f)));
        }
        *(uint2*)ab = make_uint2(pack2(fmaxf(vr[0], 0.f), fmaxf(vr[1], 0.f)),
                                 pack2(fmaxf(vr[2], 0.f), fmaxf(vr[3], 0.f)));
        #pragma unroll
        for (int s = 0; s < 4; ++s)
            *(uint2*)(ab + (1 + s) * 256) = tw[s];
    }
}

extern "C" __global__ __launch_bounds__(512, 2)
void critic_kernel(KParams p)
{
    extern __shared__ char lds[];
    const int tid  = threadIdx.x;
    const int lane = tid & 63;
    const int wave = tid >> 6;            // 0..7
    const int rowBase = blockIdx.x * TB;

    const int cb128 = wave << 4;                        // 16-col group, N=128
    const int cb64  = (wave >> 1) << 4;                 // 16-col group, final
    const int btB64 = (wave & 1) << 1;                  // row-half, final
    const uint32_t btOff64 = (uint32_t)btB64 * 20480u;

    const float m  = p.mix[0];
    const float c0 = 1.f - m;
    float cP[4];
    #pragma unroll
    for (int k = 0; k < 4; ++k) cP[k] = m * p.P[k];

    stage_xu(lds, p.x, p.u, rowBase, tid);

    #pragma unroll 1
    for (int head = 0; head < 2; ++head) {
        const unsigned short* wb = p.wbf + head * HEAD_W;
        const int hb = head * 3;
        v4f acc[5][4];

        WPre w1 = preload<128>(wb, cb128, p.mb[hb + 0], p.tb[hb + 0], lane);
        __syncthreads();                    // A: stage/restage + pgrid visible
        // L1: xu (slot 0, shared) -> acc
        mfma_phase<true, 4>(lds, 0, w1, acc, lane);
        __syncthreads();                    // B: slot-0 reads done
        write_streams(lds, acc, c0, cP, lane, cb128);   // -> slots 0..4
        WPre w2 = preload<128>(wb + 81920, cb128, p.mb[hb + 1], p.tb[hb + 1], lane);
        __syncthreads();                    // C: L1 writes visible
        // L2: slots 0..4 -> acc
        mfma_phase<false, 4>(lds, 0, w2, acc, lane);
        __syncthreads();                    // D: reads done
        write_streams(lds, acc, c0, cP, lane, cb128);   // in-place rewrite
        WPre w3 = preload<64>(wb + 163840, cb64, p.mb[hb + 2], p.tb[hb + 2], lane);
        __syncthreads();                    // E: L2 writes visible
        // L3: slots 0..4 -> acc -> register combine + Wout dot
        v4f accF[5][2];
        mfma_phase<false, 2>(lds, btOff64, w3, accF, lane);
        {
            const int obase = cb64 + ((lane >> 4) << 2);
            const float4 wo = *(const float4*)(p.Wout[head] + obase);
            float psum[2];
            #pragma unroll
            for (int j = 0; j < 2; ++j) {
                float vr[4];
                vr[0] = c0 * accF[0][j][0];
                vr[1] = c0 * accF[0][j][1];
                vr[2] = c0 * accF[0][j][2];
                vr[3] = c0 * accF[0][j][3];
                #pragma unroll
                for (int s = 0; s < 4; ++s) {
                    vr[0] = fmaf(cP[s], accF[s + 1][j][0], vr[0]);
                    vr[1] = fmaf(cP[s], accF[s + 1][j][1], vr[1]);
                    vr[2] = fmaf(cP[s], accF[s + 1][j][2], vr[2]);
                    vr[3] = fmaf(cP[s], accF[s + 1][j][3], vr[3]);
                }
                float pp = fmaxf(vr[0], 0.f) * wo.x + fmaxf(vr[1], 0.f) * wo.y
                         + fmaxf(vr[2], 0.f) * wo.z + fmaxf(vr[3], 0.f) * wo.w;
                pp += __shfl_xor(pp, 16);
                pp += __shfl_xor(pp, 32);
                psum[j] = pp;
            }
            __syncthreads();                // F: slot reads done -> may overwrite
            // pgrid at bytes [256,1280) = row-0 slots 1..4 (dead until next
            // L1 write phase, which is 2 barriers after the out-read below)
            if (lane < 16) {
                float* pgrid = (float*)(lds + 256);
                #pragma unroll
                for (int j = 0; j < 2; ++j)
                    pgrid[(cb64 >> 4) * 64 + (btB64 + j) * 16 + lane] = psum[j];
            }
        }
        if (head == 0) {
            stage_xu(lds, p.x, p.u, rowBase, tid);   // restage xu into slot 0
        }
        __syncthreads();                    // G: pgrid + restage visible
        if (tid < 64) {
            const float* pg = (const float*)(lds + 256);
            p.out[head * B_TOTAL + rowBase + tid] =
                p.bout[head][0] + pg[tid] + pg[64 + tid] + pg[128 + tid] + pg[192 + tid];
        }
    }
}

extern "C" void kernel_launch(void* const* d_in, const int* in_sizes, int n_in,
                              void* d_out, int out_size, void* d_ws, size_t ws_size,
                              hipStream_t stream)
{
    (void)in_sizes; (void)n_in; (void)out_size; (void)ws_size;

    PrepParams pp;
    const int sidx[12] = {4, 20, 6, 22, 8, 24, 12, 26, 14, 28, 16, 30};
    for (int i = 0; i < 12; ++i) pp.src[i] = (const float*)d_in[sidx[i]];
    pp.dst = (unsigned short*)d_ws;

    KParams kp;
    kp.x = (const float*)d_in[0];  kp.u = (const float*)d_in[1];
    kp.mix = (const float*)d_in[2]; kp.P = (const float*)d_in[3];
    const int mbi[6] = {5, 7, 9, 13, 15, 17};
    const int tbi[6] = {21, 23, 25, 27, 29, 31};
    for (int i = 0; i < 6; ++i) {
        kp.mb[i] = (const float*)d_in[mbi[i]];
        kp.tb[i] = (const float*)d_in[tbi[i]];
    }
    kp.Wout[0] = (const float*)d_in[10]; kp.Wout[1] = (const float*)d_in[18];
    kp.bout[0] = (const float*)d_in[11]; kp.bout[1] = (const float*)d_in[19];
    kp.wbf = (const unsigned short*)d_ws;
    kp.out = (float*)d_out;

    (void)hipFuncSetAttribute((const void*)critic_kernel,
                              hipFuncAttributeMaxDynamicSharedMemorySize, LDS_BYTES);

    hipLaunchKernelGGL(prep_kernel, dim3(400), dim3(256), 0, stream, pp);
    hipLaunchKernelGGL(critic_kernel, dim3(B_TOTAL / TB), dim3(512), LDS_BYTES, stream, kp);
}

// Round 7
// 786.505 us; speedup vs baseline: 1.6875x; 1.1109x over previous
//
#include <hip/hip_runtime.h>
#include <hip/hip_bf16.h>
#include <stdint.h>

#define B_TOTAL 262144
#define TB 64
#define RECORD 2560         // 10 stream-slots * 256B per row
#define LDS_BYTES 163840    // 64 rows * 2560 = 160 KiB exactly
#define HEAD_W 204800       // bf16 weight elements per head in d_ws

typedef short v8s __attribute__((ext_vector_type(8)));
typedef float v4f __attribute__((ext_vector_type(4)));

union Frag { uint4 q; uint32_t d[4]; v8s v; };

__device__ __forceinline__ uint32_t pack2(float a, float b) {
    union { __hip_bfloat162 h; uint32_t u; } p;
    p.h = __float22bfloat162_rn(make_float2(a, b));
    return p.u;
}

// LDS layout: addr(row, slot, gg) = row*2560 + slot*256 + ((gg ^ (row&15))<<4)
// Zero-VALU DS addressing (verified R2): swizzle folds into per-lane bases,
// slot / row-tile offsets fold into immediates / one add.
//
// Slot map (HEAD-INTERLEAVED schedule):
//   S0   : xu (read by BOTH L1 phases), then h1-main in-place after bar2
//   S1-5 : h0 streams (main, t0..t3), rewritten in-place L1->L2
//   S6-9 : h1 teachers t0..t3
//   pgrid-h0: bytes [ 256,1280) of row 0 (slots 1-4, dead after L3h0 reads)
//   pgrid-h1: bytes [1536,2560) of row 0 (slots 6-9, dead after L3h1 reads)
//
// The two heads are independent chains; each inter-barrier region holds one
// head's MFMA phase + the OTHER head's epilogue + a weight preload, so the
// compiler overlaps VALU / LDS-read / MFMA / VMEM within every region.

struct KParams {
    const float* x; const float* u; const float* mix; const float* P;
    const float* mb[6];
    const float* tb[6];
    const float* Wout[2];
    const float* bout[2];
    const unsigned short* wbf;
    float* out;
};

struct PrepParams { const float* src[12]; unsigned short* dst; };

__global__ __launch_bounds__(256) void prep_kernel(PrepParams pp) {
    const int ends[12] = {16384,81920,98304,163840,172032,204800,
                          221184,286720,303104,368640,376832,409600};
    int gi = (blockIdx.x * 256 + threadIdx.x) * 4;
    if (gi >= 409600) return;
    int s = 0;
    #pragma unroll
    for (int i = 0; i < 12; ++i) { if (gi >= ends[i]) s = i + 1; }
    int base = (s == 0) ? 0 : ends[s - 1];
    const float4 f = *(const float4*)(pp.src[s] + (gi - base));
    *(uint2*)(pp.dst + gi) = make_uint2(pack2(f.x, f.y), pack2(f.z, f.w));
}

__device__ __forceinline__ void stage_xu(char* lds, const float* x, const float* u,
                                         int rowBase, int tid)
{
    for (int G = tid; G < 1024; G += 512) {
        const int row = G >> 4;
        const int gg  = G & 15;
        const int grow = rowBase + row;
        float4 fa, fb;
        if (gg < 12) {
            const float* s2 = x + grow * 96 + gg * 8;
            fa = *(const float4*)s2; fb = *(const float4*)(s2 + 4);
        } else {
            const float* s2 = u + grow * 32 + (gg - 12) * 8;
            fa = *(const float4*)s2; fb = *(const float4*)(s2 + 4);
        }
        *(uint4*)(lds + row * RECORD + ((gg ^ (row & 15)) << 4)) =
            make_uint4(pack2(fa.x, fa.y), pack2(fa.z, fa.w),
                       pack2(fb.x, fb.y), pack2(fb.z, fb.w));
    }
}

// Full per-phase weight state in registers (R0/R2-verified shape at (512,2)).
struct WPre { Frag w[20]; float4 mB; float4 tB[4]; };

template<int N>
__device__ __forceinline__ WPre preload(const unsigned short* W, int colBase,
        const float* mbias, const float* tbias, int lane)
{
    WPre r;
    const int l15  = lane & 15;
    const int quad = lane >> 4;
    const unsigned short* wRow = W + (colBase + l15) * 128 + quad * 8;
    #pragma unroll
    for (int s = 0; s < 5; ++s)
        #pragma unroll
        for (int ks = 0; ks < 4; ++ks)
            r.w[s * 4 + ks].q = *(const uint4*)(wRow + s * (N * 128) + ks * 32);
    const int obase = colBase + quad * 4;
    r.mB = *(const float4*)(mbias + obase);
    #pragma unroll
    for (int s = 0; s < 4; ++s)
        r.tB[s] = *(const float4*)(tbias + s * N + obase);
    return r;
}

// MFMA phase: input streams -> bias-initialized acc. No LDS writes.
// Stream s reads slot (s==0 ? SM : ST+s-1). SHARED_IN: all 5 read SM (=xu).
// MFMA: A = weight frag (m = out col), B = activation frag (n = batch row).
// Acc per lane: batch row bt*16+(lane&15), out cols obase+(lane>>4)*4+r.
template<bool SHARED_IN, int SM, int ST, int NBT>
__device__ __forceinline__ void mfma_phase(const char* lds, uint32_t btOff,
        const WPre& wp, v4f (&acc)[5][NBT], int lane)
{
    const int l15  = lane & 15;
    const int quad = lane >> 4;
    const uint32_t rb = (uint32_t)l15 * RECORD + ((uint32_t)l15 << 4) + btOff;
    uint32_t rA[4];
    #pragma unroll
    for (int ks = 0; ks < 4; ++ks)
        rA[ks] = rb ^ (uint32_t)(((ks << 2) | quad) << 4);

    #pragma unroll
    for (int bt = 0; bt < NBT; ++bt) {
        acc[0][bt] = (v4f){wp.mB.x, wp.mB.y, wp.mB.z, wp.mB.w};
        #pragma unroll
        for (int s = 0; s < 4; ++s)
            acc[s + 1][bt] = (v4f){wp.tB[s].x, wp.tB[s].y, wp.tB[s].z, wp.tB[s].w};
    }

    #pragma unroll
    for (int ks = 0; ks < 4; ++ks) {
        Frag xS[NBT];
        if constexpr (SHARED_IN) {
            #pragma unroll
            for (int bt = 0; bt < NBT; ++bt)
                xS[bt].q = *(const uint4*)(lds + rA[ks]
                            + (uint32_t)(bt * 40960 + SM * 256));
        }
        #pragma unroll
        for (int s = 0; s < 5; ++s) {
            constexpr int dummy = 0; (void)dummy;
            Frag xF[NBT];
            if constexpr (!SHARED_IN) {
                const int slot = (s == 0) ? SM : (ST + s - 1);
                #pragma unroll
                for (int bt = 0; bt < NBT; ++bt)
                    xF[bt].q = *(const uint4*)(lds + rA[ks]
                                + (uint32_t)(bt * 40960 + slot * 256));
            }
            #pragma unroll
            for (int bt = 0; bt < NBT; ++bt)
                acc[s][bt] = __builtin_amdgcn_mfma_f32_16x16x32_bf16(
                    wp.w[s * 4 + ks].v, (SHARED_IN ? xS[bt].v : xF[bt].v),
                    acc[s][bt], 0, 0, 0);
        }
    }
}

// Epilogue: mix + relu, write 5 streams. Main -> slot WM, teacher s -> WT+s.
// In-place safe only after a block barrier confirming all reads of the target
// slots completed (R6-verified discipline).
template<int WM, int WT>
__device__ __forceinline__ void write_streams(char* lds, v4f (&acc)[5][4],
        float c0, const float* cP, int lane, int colBase)
{
    const int l15  = lane & 15;
    const int quad = lane >> 4;
    const uint32_t rb = (uint32_t)l15 * RECORD + ((uint32_t)l15 << 4);
    const int ocg = (colBase >> 3) + (quad >> 1);
    const uint32_t w0 = (rb ^ ((uint32_t)ocg << 4)) + (uint32_t)((quad & 1) << 3);
    #pragma unroll
    for (int bt = 0; bt < 4; ++bt) {
        char* ab = lds + (w0 + (uint32_t)(bt * 40960));
        float vr[4];
        vr[0] = c0 * acc[0][bt][0];
        vr[1] = c0 * acc[0][bt][1];
        vr[2] = c0 * acc[0][bt][2];
        vr[3] = c0 * acc[0][bt][3];
        uint2 tw[4];
        #pragma unroll
        for (int s = 0; s < 4; ++s) {
            const float t0 = acc[s + 1][bt][0];
            const float t1 = acc[s + 1][bt][1];
            const float t2 = acc[s + 1][bt][2];
            const float t3 = acc[s + 1][bt][3];
            vr[0] = fmaf(cP[s], t0, vr[0]);
            vr[1] = fmaf(cP[s], t1, vr[1]);
            vr[2] = fmaf(cP[s], t2, vr[2]);
            vr[3] = fmaf(cP[s], t3, vr[3]);
            tw[s] = make_uint2(pack2(fmaxf(t0, 0.f), fmaxf(t1, 0.f)),
                               pack2(fmaxf(t2, 0.f), fmaxf(t3, 0.f)));
        }
        *(uint2*)(ab + WM * 256) =
            make_uint2(pack2(fmaxf(vr[0], 0.f), fmaxf(vr[1], 0.f)),
                       pack2(fmaxf(vr[2], 0.f), fmaxf(vr[3], 0.f)));
        #pragma unroll
        for (int s = 0; s < 4; ++s)
            *(uint2*)(ab + (WT + s) * 256) = tw[s];
    }
}

// Final L3+L4 combine: mix + relu + Wout dot + cross-lane reduce -> pgrid.
__device__ __forceinline__ void psum_write(const v4f (&accF)[5][2], float c0,
        const float* cP, const float* Wout, float* pgrid, int lane,
        int cb64, int btB64)
{
    const int obase = cb64 + ((lane >> 4) << 2);
    const float4 wo = *(const float4*)(Wout + obase);
    #pragma unroll
    for (int j = 0; j < 2; ++j) {
        float vr[4];
        vr[0] = c0 * accF[0][j][0];
        vr[1] = c0 * accF[0][j][1];
        vr[2] = c0 * accF[0][j][2];
        vr[3] = c0 * accF[0][j][3];
        #pragma unroll
        for (int s = 0; s < 4; ++s) {
            vr[0] = fmaf(cP[s], accF[s + 1][j][0], vr[0]);
            vr[1] = fmaf(cP[s], accF[s + 1][j][1], vr[1]);
            vr[2] = fmaf(cP[s], accF[s + 1][j][2], vr[2]);
            vr[3] = fmaf(cP[s], accF[s + 1][j][3], vr[3]);
        }
        float pp = fmaxf(vr[0], 0.f) * wo.x + fmaxf(vr[1], 0.f) * wo.y
                 + fmaxf(vr[2], 0.f) * wo.z + fmaxf(vr[3], 0.f) * wo.w;
        pp += __shfl_xor(pp, 16);
        pp += __shfl_xor(pp, 32);
        if (lane < 16)
            pgrid[(cb64 >> 4) * 64 + (btB64 + j) * 16 + lane] = pp;
    }
}

extern "C" __global__ __launch_bounds__(512, 2)
void critic_kernel(KParams p)
{
    extern __shared__ char lds[];
    const int tid  = threadIdx.x;
    const int lane = tid & 63;
    const int wave = tid >> 6;            // 0..7
    const int rowBase = blockIdx.x * TB;

    const int cb128 = wave << 4;                        // 16-col group, N=128
    const int cb64  = (wave >> 1) << 4;                 // 16-col group, final
    const int btB64 = (wave & 1) << 1;                  // row-half, final
    const uint32_t btOff64 = (uint32_t)btB64 * 40960u;

    const float m  = p.mix[0];
    const float c0 = 1.f - m;
    float cP[4];
    #pragma unroll
    for (int k = 0; k < 4; ++k) cP[k] = m * p.P[k];

    const unsigned short* wb0 = p.wbf;
    const unsigned short* wb1 = p.wbf + HEAD_W;

    stage_xu(lds, p.x, p.u, rowBase, tid);
    WPre wA = preload<128>(wb0, cb128, p.mb[0], p.tb[0], lane);
    __syncthreads();                                    // bar1: xu visible

    // region 1: L1h0 (read S0) + epi -> S1-5 ; L1h1 (read S0)
    v4f accB[5][4];
    {
        WPre wB = preload<128>(wb1, cb128, p.mb[3], p.tb[3], lane);
        v4f accA[5][4];
        mfma_phase<true, 0, 0, 4>(lds, 0, wA, accA, lane);
        write_streams<1, 2>(lds, accA, c0, cP, lane, cb128);   // S1-5 dead: OK
        mfma_phase<true, 0, 0, 4>(lds, 0, wB, accB, lane);
    }
    __syncthreads();     // bar2: S0 reads done (-> in-place OK); S1-5 visible

    // region 2: L1h1 epi -> S0,S6-9 ; L2h0 (read S1-5)
    v4f accC[5][4];
    {
        WPre wC = preload<128>(wb0 + 81920, cb128, p.mb[1], p.tb[1], lane);
        write_streams<0, 6>(lds, accB, c0, cP, lane, cb128);
        mfma_phase<false, 1, 2, 4>(lds, 0, wC, accC, lane);
    }
    __syncthreads();     // bar3: S1-5 reads done; S0,S6-9 visible

    // region 3: L2h0 epi in-place S1-5 ; L2h1 (read S0,S6-9)
    v4f accD[5][4];
    {
        WPre wD = preload<128>(wb1 + 81920, cb128, p.mb[4], p.tb[4], lane);
        write_streams<1, 2>(lds, accC, c0, cP, lane, cb128);
        mfma_phase<false, 0, 6, 4>(lds, 0, wD, accD, lane);
    }
    __syncthreads();     // bar4: S0,S6-9 reads done; S1-5 visible

    // region 4: L2h1 epi in-place S0,S6-9 ; L3h0 (read S1-5)
    v4f accE[5][2];
    {
        WPre wE = preload<64>(wb0 + 163840, cb64, p.mb[2], p.tb[2], lane);
        write_streams<0, 6>(lds, accD, c0, cP, lane, cb128);
        mfma_phase<false, 1, 2, 2>(lds, btOff64, wE, accE, lane);
    }
    __syncthreads();     // bar5: S1-5 reads done; S0,S6-9 visible

    // region 5: h0 psum -> pgrid (S1-4 row0) ; L3h1 (read S0,S6-9)
    v4f accF[5][2];
    {
        WPre wF = preload<64>(wb1 + 163840, cb64, p.mb[5], p.tb[5], lane);
        psum_write(accE, c0, cP, p.Wout[0], (float*)(lds + 256),
                   lane, cb64, btB64);
        mfma_phase<false, 0, 6, 2>(lds, btOff64, wF, accF, lane);
    }
    __syncthreads();     // bar6: S0,S6-9 reads done; pgrid-h0 visible

    // out-h0 ; h1 psum -> pgrid (S6-9 row0, disjoint from out-h0 reads)
    if (tid < 64) {
        const float* pg = (const float*)(lds + 256);
        p.out[rowBase + tid] =
            p.bout[0][0] + pg[tid] + pg[64 + tid] + pg[128 + tid] + pg[192 + tid];
    }
    psum_write(accF, c0, cP, p.Wout[1], (float*)(lds + 1536),
               lane, cb64, btB64);
    __syncthreads();     // bar7: pgrid-h1 visible

    if (tid < 64) {
        const float* pg = (const float*)(lds + 1536);
        p.out[B_TOTAL + rowBase + tid] =
            p.bout[1][0] + pg[tid] + pg[64 + tid] + pg[128 + tid] + pg[192 + tid];
    }
}

extern "C" void kernel_launch(void* const* d_in, const int* in_sizes, int n_in,
                              void* d_out, int out_size, void* d_ws, size_t ws_size,
                              hipStream_t stream)
{
    (void)in_sizes; (void)n_in; (void)out_size; (void)ws_size;

    PrepParams pp;
    const int sidx[12] = {4, 20, 6, 22, 8, 24, 12, 26, 14, 28, 16, 30};
    for (int i = 0; i < 12; ++i) pp.src[i] = (const float*)d_in[sidx[i]];
    pp.dst = (unsigned short*)d_ws;

    KParams kp;
    kp.x = (const float*)d_in[0];  kp.u = (const float*)d_in[1];
    kp.mix = (const float*)d_in[2]; kp.P = (const float*)d_in[3];
    const int mbi[6] = {5, 7, 9, 13, 15, 17};
    const int tbi[6] = {21, 23, 25, 27, 29, 31};
    for (int i = 0; i < 6; ++i) {
        kp.mb[i] = (const float*)d_in[mbi[i]];
        kp.tb[i] = (const float*)d_in[tbi[i]];
    }
    kp.Wout[0] = (const float*)d_in[10]; kp.Wout[1] = (const float*)d_in[18];
    kp.bout[0] = (const float*)d_in[11]; kp.bout[1] = (const float*)d_in[19];
    kp.wbf = (const unsigned short*)d_ws;
    kp.out = (float*)d_out;

    (void)hipFuncSetAttribute((const void*)critic_kernel,
                              hipFuncAttributeMaxDynamicSharedMemorySize, LDS_BYTES);

    hipLaunchKernelGGL(prep_kernel, dim3(400), dim3(256), 0, stream, pp);
    hipLaunchKernelGGL(critic_kernel, dim3(B_TOTAL / TB), dim3(512), LDS_BYTES, stream, kp);
}